// Round 10
// baseline (68.882 us; speedup 1.0000x reference)
//
#include <hip/hip_runtime.h>
#include <math.h>

// Problem constants (D_IN == D_OUT == 4096)
constexpr int   D     = 4096;
constexpr float ALPHA = 0.001f;   // heb_lr
constexpr float GAMMA = 0.99f;
constexpr float EPSC  = 0.0001f;

// --- main path decomposition ---
constexpr int RG    = 8;               // rows per k_gz block (P granularity)
constexpr int NPR   = D / RG;          // 512 P rows
constexpr int SUB   = 4;               // rows per LDS sub-batch (64 KB tile)
constexpr int GSZ2  = 16;              // P rows per supersum group
constexpr int NSS   = NPR / GSZ2;      // 32 SS rows
constexpr int RCH3  = 32;              // k_update rows per chunk
constexpr int NCH3  = D / RCH3;        // 128
constexpr int TPB3  = 256;

using vf4 = float __attribute__((ext_vector_type(4)));

// ---------------------------------------------------------------------------
// K1: fused GEMV + chunk column-partials via LDS staging (z-units), with a
// T14 register prefetch of sub-batch 1 under sub-batch 0's LDS accumulate,
// and a group-finisher epilogue that computes SS (replaces the k_mid launch).
//
// Finisher protocol (R2-proven agent-scope pattern, no spinning): P payload
// written with relaxed agent atomic stores; ACQ_REL fetch_add on the group
// counter; the block seeing old%16==15 (exactly one per call, for ANY
// initial counter value -- poison-proof, no reset needed) re-reads the
// group's 16 P rows via relaxed agent atomic loads and writes SS. Sum order
// is fixed (rows 0..15) -> bitwise deterministic.
// ---------------------------------------------------------------------------
__global__ __launch_bounds__(256, 2) void k_gz(const float* __restrict__ W,
                                               const float* __restrict__ x,
                                               const float* __restrict__ b,
                                               float* __restrict__ z_out,
                                               float* __restrict__ P,
                                               float* __restrict__ SS,
                                               unsigned* __restrict__ cnt) {
    const int tid  = threadIdx.x;
    const int lane = tid & 63;
    const int wv   = tid >> 6;            // 0..3
    const int c    = blockIdx.x;          // P row (8-row chunk)
    const int k0   = c * RG;

    __shared__ float4   tile[SUB * 1024];   // 64 KB
    __shared__ float    sz[SUB];
    __shared__ unsigned s_fin;

    const float4* xv = reinterpret_cast<const float4*>(x);
    float4 acc[4] = {make_float4(0.f, 0.f, 0.f, 0.f),
                     make_float4(0.f, 0.f, 0.f, 0.f),
                     make_float4(0.f, 0.f, 0.f, 0.f),
                     make_float4(0.f, 0.f, 0.f, 0.f)};

    // ---- Stage A: sub-batch 0 -> tile + dot ----
    {
        const int row = k0 + wv;
        const float4* Wr = reinterpret_cast<const float4*>(W + (size_t)row * D);
        float a = 0.f;
        #pragma unroll
        for (int q = 0; q < 16; ++q) {
            const float4 w = Wr[lane + q * 64];
            tile[wv * 1024 + lane + q * 64] = w;
            const float4 xx = xv[lane + q * 64];
            a += w.x * xx.x + w.y * xx.y + w.z * xx.z + w.w * xx.w;
        }
        #pragma unroll
        for (int off = 32; off; off >>= 1) a += __shfl_down(a, off, 64);
        if (lane == 0) {
            const float u = a + b[row];
            const float r = fmaxf(u, 0.f);
            const float zz = r * r;              // z = relu(u)^2 (LAMB = 2)
            sz[wv] = zz;
            z_out[row] = zz;
        }
    }
    __syncthreads();                             // tile + sz ready

    // ---- Stage B: prefetch sub-batch 1 to regs; accumulate sub-batch 0 ----
    float4 r1[16];                               // 64 VGPRs, statically indexed
    const int row1 = k0 + SUB + wv;
    {
        const float4* Wr1 = reinterpret_cast<const float4*>(W + (size_t)row1 * D);
        #pragma unroll
        for (int q = 0; q < 16; ++q) r1[q] = Wr1[lane + q * 64];  // issue early
    }
    #pragma unroll
    for (int c4 = 0; c4 < 4; ++c4) {             // hides the loads above
        const int col = tid + c4 * 256;
        #pragma unroll
        for (int r = 0; r < SUB; ++r) {
            const float4 w = tile[r * 1024 + col];
            const float zz = sz[r];
            acc[c4].x += zz * w.x; acc[c4].y += zz * w.y;
            acc[c4].z += zz * w.z; acc[c4].w += zz * w.w;
        }
    }
    float a1 = 0.f;
    #pragma unroll
    for (int q = 0; q < 16; ++q) {
        const float4 xx = xv[lane + q * 64];
        a1 += r1[q].x * xx.x + r1[q].y * xx.y + r1[q].z * xx.z + r1[q].w * xx.w;
    }
    __syncthreads();                             // done reading tile (it=0)

    // ---- Stage C: sub-batch 1 -> tile; z ----
    #pragma unroll
    for (int q = 0; q < 16; ++q) tile[wv * 1024 + lane + q * 64] = r1[q];
    #pragma unroll
    for (int off = 32; off; off >>= 1) a1 += __shfl_down(a1, off, 64);
    if (lane == 0) {
        const float u = a1 + b[row1];
        const float r = fmaxf(u, 0.f);
        const float zz = r * r;
        sz[wv] = zz;
        z_out[row1] = zz;
    }
    __syncthreads();

    // ---- Stage D: accumulate sub-batch 1; write P (agent-visible) ----
    #pragma unroll
    for (int c4 = 0; c4 < 4; ++c4) {
        const int col = tid + c4 * 256;
        #pragma unroll
        for (int r = 0; r < SUB; ++r) {
            const float4 w = tile[r * 1024 + col];
            const float zz = sz[r];
            acc[c4].x += zz * w.x; acc[c4].y += zz * w.y;
            acc[c4].z += zz * w.z; acc[c4].w += zz * w.w;
        }
    }
    {
        float* Pr = P + (size_t)c * D;
        #pragma unroll
        for (int c4 = 0; c4 < 4; ++c4) {
            const int col4 = (tid + c4 * 256) * 4;
            __hip_atomic_store(Pr + col4 + 0, acc[c4].x, __ATOMIC_RELAXED, __HIP_MEMORY_SCOPE_AGENT);
            __hip_atomic_store(Pr + col4 + 1, acc[c4].y, __ATOMIC_RELAXED, __HIP_MEMORY_SCOPE_AGENT);
            __hip_atomic_store(Pr + col4 + 2, acc[c4].z, __ATOMIC_RELAXED, __HIP_MEMORY_SCOPE_AGENT);
            __hip_atomic_store(Pr + col4 + 3, acc[c4].w, __ATOMIC_RELAXED, __HIP_MEMORY_SCOPE_AGENT);
        }
    }
    __syncthreads();                             // all P stores issued

    // ---- Epilogue: group finisher computes SS[g,:] ----
    const int g = c >> 4;                        // c / GSZ2
    if (tid == 0) {
        const unsigned old = __hip_atomic_fetch_add(&cnt[g], 1u, __ATOMIC_ACQ_REL,
                                                    __HIP_MEMORY_SCOPE_AGENT);
        s_fin = ((old & (GSZ2 - 1)) == GSZ2 - 1) ? 1u : 0u;
    }
    __syncthreads();
    if (s_fin) {
        const float* Pg = P + (size_t)(g * GSZ2) * D;
        float* SSg = SS + (size_t)g * D;
        #pragma unroll
        for (int c4 = 0; c4 < 4; ++c4) {
            const int col4 = (tid + c4 * 256) * 4;
            float ax = 0.f, ay = 0.f, az = 0.f, aw = 0.f;
            for (int i = 0; i < GSZ2; ++i) {
                const float* p = Pg + (size_t)i * D + col4;
                ax += __hip_atomic_load(p + 0, __ATOMIC_RELAXED, __HIP_MEMORY_SCOPE_AGENT);
                ay += __hip_atomic_load(p + 1, __ATOMIC_RELAXED, __HIP_MEMORY_SCOPE_AGENT);
                az += __hip_atomic_load(p + 2, __ATOMIC_RELAXED, __HIP_MEMORY_SCOPE_AGENT);
                aw += __hip_atomic_load(p + 3, __ATOMIC_RELAXED, __HIP_MEMORY_SCOPE_AGENT);
            }
            *reinterpret_cast<float4*>(SSg + col4) = make_float4(ax, ay, az, aw);
        }
    }
}

// ---------------------------------------------------------------------------
// K2: redundant per-block stats (bitwise-identical reduction order; R5/R6
// proven) + two-level exclusive prefix (SS + <=12 P slices, L2-resident) +
// in-chunk inclusive scan + Hebbian delta + sign-split decay + nt W2 store.
// t==0 blocks write the y/ea outputs for their chunk rows.
// ---------------------------------------------------------------------------
__global__ __launch_bounds__(TPB3) void k_update(const float* __restrict__ W,
                                                 const float* __restrict__ x,
                                                 const float* __restrict__ z,
                                                 const float* __restrict__ ea,
                                                 const float* __restrict__ P,
                                                 const float* __restrict__ SS,
                                                 float* __restrict__ y_out,
                                                 float* __restrict__ ea_out,
                                                 float* __restrict__ W2) {
    const int tid  = threadIdx.x;
    const int t    = blockIdx.x;
    const int c    = blockIdx.y;           // 32-row chunk, 0..127
    const int j4   = t * TPB3 + tid;       // float4 column
    const int k0   = c * RCH3;
    const int wv   = tid >> 6;
    const int lane = tid & 63;

    __shared__ float sred[4];
    __shared__ float sm[2];                // m^2, sum(ea_new)
    __shared__ float sy[RCH3], sgp[RCH3], sgn[RCH3];

    // stats pass 1: m^2 = max(z) (square is monotone on relu output)
    float lmax = 0.f;
    #pragma unroll
    for (int i = 0; i < D / TPB3; ++i)
        lmax = fmaxf(lmax, z[i * TPB3 + tid]);
    #pragma unroll
    for (int off = 32; off; off >>= 1) lmax = fmaxf(lmax, __shfl_down(lmax, off, 64));
    if (lane == 0) sred[wv] = lmax;
    __syncthreads();
    if (tid == 0) sm[0] = fmaxf(fmaxf(sred[0], sred[1]), fmaxf(sred[2], sred[3]));
    __syncthreads();
    const float inv_m2 = 1.f / sm[0];

    // stats pass 2: sum(ea_new)
    float lsum = 0.f;
    #pragma unroll
    for (int i = 0; i < D / TPB3; ++i) {
        const int r = i * TPB3 + tid;
        lsum += GAMMA * ea[r] + (1.f - GAMMA) * (z[r] * inv_m2);
    }
    #pragma unroll
    for (int off = 32; off; off >>= 1) lsum += __shfl_down(lsum, off, 64);
    if (lane == 0) sred[wv] = lsum;        // safe: all passed prior sync
    __syncthreads();
    if (tid == 0) sm[1] = (sred[0] + sred[1]) + (sred[2] + sred[3]);
    __syncthreads();
    const float inv_avg = (float)D / sm[1];

    // own-chunk y / gf; t==0 blocks write y / ea globals
    if (tid < RCH3) {
        const int r = k0 + tid;
        const float yv = z[r] * inv_m2;
        const float ev = GAMMA * ea[r] + (1.f - GAMMA) * yv;
        const float aa = ev * inv_avg;
        const float gg = EPSC * tanhf(-EPSC * (aa - 1.f)) + 1.f;
        sy[tid]  = yv;
        sgp[tid] = gg;
        sgn[tid] = 1.f / gg;
        if (t == 0) { y_out[r] = yv; ea_out[r] = ev; }
    }
    __syncthreads();

    // two-level exclusive prefix in z-units.
    const int g3 = c >> 2;                 // full SS groups (16 P rows each)
    float4 a0 = make_float4(0.f, 0.f, 0.f, 0.f);
    float4 a1 = make_float4(0.f, 0.f, 0.f, 0.f);
    {
        const float4* SSp = reinterpret_cast<const float4*>(SS) + j4;
        int i = 0;
        #pragma unroll 4
        for (; i + 2 <= g3; i += 2) {
            const float4 p0 = SSp[(size_t)i * (D / 4)];
            const float4 p1 = SSp[(size_t)(i + 1) * (D / 4)];
            a0.x += p0.x; a0.y += p0.y; a0.z += p0.z; a0.w += p0.w;
            a1.x += p1.x; a1.y += p1.y; a1.z += p1.z; a1.w += p1.w;
        }
        if (i < g3) {
            const float4 p0 = SSp[(size_t)i * (D / 4)];
            a0.x += p0.x; a0.y += p0.y; a0.z += p0.z; a0.w += p0.w;
        }
    }
    {
        const float4* Pp = reinterpret_cast<const float4*>(P) + j4;
        int i = g3 * GSZ2;
        const int iend = 4 * c;            // P rows before this 32-row chunk
        #pragma unroll 4
        for (; i + 2 <= iend; i += 2) {
            const float4 p0 = Pp[(size_t)i * (D / 4)];
            const float4 p1 = Pp[(size_t)(i + 1) * (D / 4)];
            a0.x += p0.x; a0.y += p0.y; a0.z += p0.z; a0.w += p0.w;
            a1.x += p1.x; a1.y += p1.y; a1.z += p1.z; a1.w += p1.w;
        }
        if (i < iend) {
            const float4 p0 = Pp[(size_t)i * (D / 4)];
            a0.x += p0.x; a0.y += p0.y; a0.z += p0.z; a0.w += p0.w;
        }
    }
    float4 s;                               // prefix converted to y-units
    s.x = (a0.x + a1.x) * inv_m2; s.y = (a0.y + a1.y) * inv_m2;
    s.z = (a0.z + a1.z) * inv_m2; s.w = (a0.w + a1.w) * inv_m2;

    const float4 xvv = reinterpret_cast<const float4*>(x)[j4];
    const float4* Wp  = reinterpret_cast<const float4*>(W  + (size_t)k0 * D) + j4;
    float4*       W2p = reinterpret_cast<float4*>(W2 + (size_t)k0 * D) + j4;
    #pragma unroll 4
    for (int k = 0; k < RCH3; ++k) {
        const float yv = sy[k];
        const float gp = sgp[k];
        const float gn = sgn[k];
        const float4 w = Wp[(size_t)k * (D / 4)];
        s.x += yv * w.x; s.y += yv * w.y;
        s.z += yv * w.z; s.w += yv * w.w;
        vf4 o;
        {
            const float w1 = w.x + ALPHA * (yv * xvv.x - yv * s.x);
            o.x = w1 * (w1 > 0.f ? gp : gn);
        }
        {
            const float w1 = w.y + ALPHA * (yv * xvv.y - yv * s.y);
            o.y = w1 * (w1 > 0.f ? gp : gn);
        }
        {
            const float w1 = w.z + ALPHA * (yv * xvv.z - yv * s.z);
            o.z = w1 * (w1 > 0.f ? gp : gn);
        }
        {
            const float w1 = w.w + ALPHA * (yv * xvv.w - yv * s.w);
            o.w = w1 * (w1 > 0.f ? gp : gn);
        }
        __builtin_nontemporal_store(o, reinterpret_cast<vf4*>(W2p + (size_t)k * (D / 4)));
    }
}

// ===========================================================================
// Fallback (proven R6-style structure) if ws_size can't hold the 8.5 MB P/SS.
// ===========================================================================
constexpr int FCH  = 64;
constexpr int FNCH = D / FCH;
constexpr int FTPB = 128;

__global__ __launch_bounds__(256) void f_gemv(const float* __restrict__ W,
                                              const float* __restrict__ x,
                                              const float* __restrict__ b,
                                              float* __restrict__ u) {
    const int wave = threadIdx.x >> 6;
    const int lane = threadIdx.x & 63;
    const int row  = (blockIdx.x << 2) + wave;
    const float4* Wr = reinterpret_cast<const float4*>(W + (size_t)row * D);
    const float4* xv = reinterpret_cast<const float4*>(x);
    float acc = 0.f;
    #pragma unroll
    for (int it = 0; it < D / 256; ++it) {
        const float4 w  = Wr[lane + it * 64];
        const float4 xx = xv[lane + it * 64];
        acc += w.x * xx.x + w.y * xx.y + w.z * xx.z + w.w * xx.w;
    }
    #pragma unroll
    for (int off = 32; off; off >>= 1) acc += __shfl_down(acc, off, 64);
    if (lane == 0) u[row] = acc + b[row];
}

__global__ __launch_bounds__(FTPB) void f_pstats(const float* __restrict__ u,
                                                 const float* __restrict__ ea,
                                                 const float* __restrict__ W,
                                                 float* __restrict__ y_out,
                                                 float* __restrict__ ea_out,
                                                 float* __restrict__ gfp,
                                                 float* __restrict__ gfn,
                                                 float* __restrict__ P) {
    const int tid  = threadIdx.x;
    const int t    = blockIdx.x;
    const int c    = blockIdx.y;
    const int j    = t * (FTPB * 4) + tid * 4;
    const int k0   = c * FCH;
    const int wv   = tid >> 6;
    const int lane = tid & 63;

    __shared__ float sred[2];
    __shared__ float sm[2];
    __shared__ float sy[FCH];

    float lmax = 0.f;
    #pragma unroll
    for (int i = 0; i < D / FTPB; ++i)
        lmax = fmaxf(lmax, u[i * FTPB + tid]);
    #pragma unroll
    for (int off = 32; off; off >>= 1) lmax = fmaxf(lmax, __shfl_down(lmax, off, 64));
    if (lane == 0) sred[wv] = lmax;
    __syncthreads();
    if (tid == 0) sm[0] = fmaxf(sred[0], sred[1]);
    __syncthreads();
    const float m = sm[0];
    const float inv_m2 = 1.f / (m * m);

    float lsum = 0.f;
    #pragma unroll
    for (int i = 0; i < D / FTPB; ++i) {
        const int r  = i * FTPB + tid;
        const float rr = fmaxf(u[r], 0.f);
        lsum += GAMMA * ea[r] + (1.f - GAMMA) * (rr * rr * inv_m2);
    }
    #pragma unroll
    for (int off = 32; off; off >>= 1) lsum += __shfl_down(lsum, off, 64);
    if (lane == 0) sred[wv] = lsum;
    __syncthreads();
    if (tid == 0) sm[1] = sred[0] + sred[1];
    __syncthreads();
    const float inv_avg = (float)D / sm[1];

    if (tid < FCH) {
        const int r = k0 + tid;
        const float rr = fmaxf(u[r], 0.f);
        const float yv = rr * rr * inv_m2;
        sy[tid] = yv;
        if (t == 0) {
            const float ev = GAMMA * ea[r] + (1.f - GAMMA) * yv;
            const float a  = ev * inv_avg;
            const float g  = EPSC * tanhf(-EPSC * (a - 1.f)) + 1.f;
            y_out[r]  = yv;
            ea_out[r] = ev;
            gfp[r]    = g;
            gfn[r]    = 1.f / g;
        }
    }
    __syncthreads();

    const float4* Wp = reinterpret_cast<const float4*>(W + (size_t)k0 * D + j);
    float4 acc = make_float4(0.f, 0.f, 0.f, 0.f);
    #pragma unroll 8
    for (int k = 0; k < FCH; ++k) {
        const float yv = sy[k];
        const float4 w = Wp[(size_t)k * (D / 4)];
        acc.x += yv * w.x; acc.y += yv * w.y;
        acc.z += yv * w.z; acc.w += yv * w.w;
    }
    *reinterpret_cast<float4*>(P + (size_t)c * D + j) = acc;
}

__global__ __launch_bounds__(FTPB) void f_update(const float* __restrict__ W,
                                                 const float* __restrict__ x,
                                                 const float* __restrict__ y,
                                                 const float* __restrict__ P,
                                                 const float* __restrict__ gfp,
                                                 const float* __restrict__ gfn,
                                                 float* __restrict__ W2) {
    const int tid = threadIdx.x;
    const int j   = blockIdx.x * (FTPB * 4) + tid * 4;
    const int c   = blockIdx.y;
    const int k0  = c * FCH;

    __shared__ float sy[FCH], sgp[FCH], sgn[FCH];
    if (tid < FCH) {
        const int r = k0 + tid;
        sy[tid]  = y[r];
        sgp[tid] = gfp[r];
        sgn[tid] = gfn[r];
    }
    __syncthreads();

    const float4* Pp = reinterpret_cast<const float4*>(P + j);
    float4 a0 = make_float4(0.f, 0.f, 0.f, 0.f);
    float4 a1 = make_float4(0.f, 0.f, 0.f, 0.f);
    int i = 0;
    #pragma unroll 8
    for (; i + 2 <= c; i += 2) {
        const float4 p0 = Pp[(size_t)i * (D / 4)];
        const float4 p1 = Pp[(size_t)(i + 1) * (D / 4)];
        a0.x += p0.x; a0.y += p0.y; a0.z += p0.z; a0.w += p0.w;
        a1.x += p1.x; a1.y += p1.y; a1.z += p1.z; a1.w += p1.w;
    }
    if (i < c) {
        const float4 p0 = Pp[(size_t)i * (D / 4)];
        a0.x += p0.x; a0.y += p0.y; a0.z += p0.z; a0.w += p0.w;
    }
    float4 s;
    s.x = a0.x + a1.x; s.y = a0.y + a1.y;
    s.z = a0.z + a1.z; s.w = a0.w + a1.w;

    const float4 xv = *reinterpret_cast<const float4*>(x + j);
    const float4* Wp  = reinterpret_cast<const float4*>(W + (size_t)k0 * D + j);
    float4*       W2p = reinterpret_cast<float4*>(W2 + (size_t)k0 * D + j);
    #pragma unroll 4
    for (int k = 0; k < FCH; ++k) {
        const float yv = sy[k];
        const float gp = sgp[k];
        const float gn = sgn[k];
        const float4 w = Wp[(size_t)k * (D / 4)];
        s.x += yv * w.x; s.y += yv * w.y;
        s.z += yv * w.z; s.w += yv * w.w;
        vf4 o;
        { const float w1 = w.x + ALPHA * (yv * xv.x - yv * s.x); o.x = w1 * (w1 > 0.f ? gp : gn); }
        { const float w1 = w.y + ALPHA * (yv * xv.y - yv * s.y); o.y = w1 * (w1 > 0.f ? gp : gn); }
        { const float w1 = w.z + ALPHA * (yv * xv.z - yv * s.z); o.z = w1 * (w1 > 0.f ? gp : gn); }
        { const float w1 = w.w + ALPHA * (yv * xv.w - yv * s.w); o.w = w1 * (w1 > 0.f ? gp : gn); }
        __builtin_nontemporal_store(o, reinterpret_cast<vf4*>(W2p + (size_t)k * (D / 4)));
    }
}

// ===========================================================================
extern "C" void kernel_launch(void* const* d_in, const int* in_sizes, int n_in,
                              void* d_out, int out_size, void* d_ws, size_t ws_size,
                              hipStream_t stream) {
    const float* x  = (const float*)d_in[0];
    const float* W  = (const float*)d_in[1];
    const float* b  = (const float*)d_in[2];
    const float* ea = (const float*)d_in[3];

    float* out    = (float*)d_out;
    float* y_out  = out;                        // [D]
    float* W2_out = out + D;                    // [D*D]
    float* ea_out = out + D + (size_t)D * D;    // [D]

    float* ws = (float*)d_ws;
    const size_t need = (size_t)(D + 64 + (size_t)NPR * D + (size_t)NSS * D)
                        * sizeof(float);

    if (ws_size >= need) {
        float*    z   = ws;                     // [D]         16 KB
        unsigned* cnt = (unsigned*)(z + D);     // [NSS] (pad to 64)
        float*    P   = z + D + 64;             // [NPR * D]   8 MB
        float*    SS  = P + (size_t)NPR * D;    // [NSS * D]   512 KB

        k_gz<<<NPR, 256, 0, stream>>>(W, x, b, z, P, SS, cnt);
        k_update<<<dim3(4, NCH3), TPB3, 0, stream>>>(W, x, z, ea, P, SS,
                                                     y_out, ea_out, W2_out);
    } else {
        float* u   = ws;                        // [D]
        float* gfp = ws + D;                    // [D]
        float* gfn = ws + 2 * D;                // [D]
        float* P   = ws + 3 * D;                // [FNCH * D] = 1 MB

        f_gemv<<<D / 4, 256, 0, stream>>>(W, x, b, u);
        dim3 grid(D / (FTPB * 4), FNCH);
        f_pstats<<<grid, FTPB, 0, stream>>>(u, ea, W, y_out, ea_out, gfp, gfn, P);
        f_update<<<grid, FTPB, 0, stream>>>(W, x, y_out, P, gfp, gfn, W2_out);
    }
}

// Round 11
// 46.670 us; speedup vs baseline: 1.4759x; 1.4759x over previous
//
#include <hip/hip_runtime.h>
#include <math.h>

// Problem constants (D_IN == D_OUT == 4096)
constexpr int   D     = 4096;
constexpr float ALPHA = 0.001f;   // heb_lr
constexpr float GAMMA = 0.99f;
constexpr float EPSC  = 0.0001f;

// --- main path decomposition ---
constexpr int RG    = 8;               // rows per k_gz block (P granularity)
constexpr int NPR   = D / RG;          // 512 P rows
constexpr int SUB   = 4;               // rows per LDS sub-batch (64 KB tile)
constexpr int NIT   = RG / SUB;        // 2 iterations
constexpr int GSZ2  = 16;              // P rows per supersum group
constexpr int NSS   = NPR / GSZ2;      // 32 SS rows
constexpr int RCH3  = 16;              // k_update rows per chunk (R11: was 32)
constexpr int NCH3  = D / RCH3;        // 256 -> 1024 blocks, 4/CU, 16 waves/CU
constexpr int TPB3  = 256;

using vf4 = float __attribute__((ext_vector_type(4)));

// ---------------------------------------------------------------------------
// K1: fused GEMV + chunk column-partials via LDS staging (z-units).
// Per 4-row sub-batch: wave w streams row w from HBM (computing the dot) and
// ds_writes it to a [4][4096] LDS tile; after z = relu(u+b)^2, all threads
// accumulate z-weighted column partials from LDS into persistent registers.
// W is read from HBM exactly once; 64 KB LDS -> 2 blocks/CU overlap phases.
// (R9-proven; R10's atomic-store variant forced P to HBM and regressed.)
// ---------------------------------------------------------------------------
__global__ __launch_bounds__(256, 2) void k_gz(const float* __restrict__ W,
                                               const float* __restrict__ x,
                                               const float* __restrict__ b,
                                               float* __restrict__ z_out,
                                               float* __restrict__ P) {
    const int tid  = threadIdx.x;
    const int lane = tid & 63;
    const int wv   = tid >> 6;            // 0..3
    const int c    = blockIdx.x;          // P row (8-row chunk)
    const int k0   = c * RG;

    __shared__ float4 tile[SUB * 1024];   // 64 KB
    __shared__ float  sz[SUB];

    const float4* xv = reinterpret_cast<const float4*>(x);
    float4 acc[4] = {make_float4(0.f, 0.f, 0.f, 0.f),
                     make_float4(0.f, 0.f, 0.f, 0.f),
                     make_float4(0.f, 0.f, 0.f, 0.f),
                     make_float4(0.f, 0.f, 0.f, 0.f)};

    #pragma unroll
    for (int it = 0; it < NIT; ++it) {
        const int row = k0 + it * SUB + wv;
        const float4* Wr = reinterpret_cast<const float4*>(W + (size_t)row * D);
        float a = 0.f;
        #pragma unroll
        for (int q = 0; q < 16; ++q) {          // 64 lanes x 16 float4 = row
            const float4 w  = Wr[lane + q * 64];
            tile[wv * 1024 + lane + q * 64] = w;
            const float4 xx = xv[lane + q * 64];
            a += w.x * xx.x + w.y * xx.y + w.z * xx.z + w.w * xx.w;
        }
        #pragma unroll
        for (int off = 32; off; off >>= 1) a += __shfl_down(a, off, 64);
        if (lane == 0) {
            const float u = a + b[row];
            const float r = fmaxf(u, 0.f);
            const float zz = r * r;              // z = relu(u)^2 (LAMB = 2)
            sz[wv] = zz;
            z_out[row] = zz;
        }
        __syncthreads();                         // tile + sz ready

        #pragma unroll
        for (int c4 = 0; c4 < 4; ++c4) {
            const int col = tid + c4 * 256;
            #pragma unroll
            for (int r = 0; r < SUB; ++r) {
                const float4 w = tile[r * 1024 + col];
                const float zz = sz[r];
                acc[c4].x += zz * w.x; acc[c4].y += zz * w.y;
                acc[c4].z += zz * w.z; acc[c4].w += zz * w.w;
            }
        }
        __syncthreads();                         // done reading before overwrite
    }

    float4* Pp = reinterpret_cast<float4*>(P + (size_t)c * D);
    #pragma unroll
    for (int c4 = 0; c4 < 4; ++c4) Pp[tid + c4 * 256] = acc[c4];
}

// ---------------------------------------------------------------------------
// K2: parallel group super-sums SS[g,:] = sum of 16 P rows, plus ONE stats
// block (m^2 = max(z), ea_new, avg, gf factors, y/ea outputs). No chains.
// ---------------------------------------------------------------------------
__global__ __launch_bounds__(256) void k_mid(const float* __restrict__ P,
                                             const float* __restrict__ z,
                                             const float* __restrict__ ea,
                                             float* __restrict__ SS,
                                             float* __restrict__ y_out,
                                             float* __restrict__ ea_out,
                                             float* __restrict__ gfp,
                                             float* __restrict__ gfn,
                                             float* __restrict__ sc) {
    const int tid = threadIdx.x;
    const int g   = blockIdx.y;
    const int bx  = blockIdx.x;

    if (g < NSS) {                         // super-sum block
        const int j4 = bx * 256 + tid;
        const float4* Pp = reinterpret_cast<const float4*>(P)
                         + (size_t)(g * GSZ2) * (D / 4) + j4;
        float4 a = make_float4(0.f, 0.f, 0.f, 0.f);
        #pragma unroll
        for (int i = 0; i < GSZ2; ++i) {
            const float4 p = Pp[(size_t)i * (D / 4)];
            a.x += p.x; a.y += p.y; a.z += p.z; a.w += p.w;
        }
        reinterpret_cast<float4*>(SS)[(size_t)g * (D / 4) + j4] = a;
        return;
    }
    if (bx != 0) return;                   // stats: single block

    __shared__ float sred[4];
    __shared__ float sm[2];
    const int wv   = tid >> 6;
    const int lane = tid & 63;

    float lmax = 0.f;
    #pragma unroll
    for (int i = 0; i < D / 256; ++i)
        lmax = fmaxf(lmax, z[i * 256 + tid]);
    #pragma unroll
    for (int off = 32; off; off >>= 1) lmax = fmaxf(lmax, __shfl_down(lmax, off, 64));
    if (lane == 0) sred[wv] = lmax;
    __syncthreads();
    if (tid == 0) sm[0] = fmaxf(fmaxf(sred[0], sred[1]), fmaxf(sred[2], sred[3]));
    __syncthreads();
    const float inv_m2 = 1.f / sm[0];

    float lsum = 0.f;
    #pragma unroll
    for (int i = 0; i < D / 256; ++i) {
        const int r = i * 256 + tid;
        lsum += GAMMA * ea[r] + (1.f - GAMMA) * (z[r] * inv_m2);
    }
    #pragma unroll
    for (int off = 32; off; off >>= 1) lsum += __shfl_down(lsum, off, 64);
    if (lane == 0) sred[wv] = lsum;
    __syncthreads();
    if (tid == 0) sm[1] = (sred[0] + sred[1]) + (sred[2] + sred[3]);
    __syncthreads();
    const float inv_avg = (float)D / sm[1];

    #pragma unroll
    for (int i = 0; i < D / 256; ++i) {
        const int r = i * 256 + tid;
        const float yv = z[r] * inv_m2;
        const float ev = GAMMA * ea[r] + (1.f - GAMMA) * yv;
        const float aa = ev * inv_avg;
        const float gg = EPSC * tanhf(-EPSC * (aa - 1.f)) + 1.f;
        y_out[r]  = yv;
        ea_out[r] = ev;
        gfp[r]    = gg;
        gfn[r]    = 1.f / gg;
    }
    if (tid == 0) sc[0] = inv_m2;
}

// ---------------------------------------------------------------------------
// K3: two-level exclusive prefix (<=31 SS + <=14 P slices, L2-resident),
// in-chunk inclusive scan, Hebbian delta + sign-split decay, nt W2 store.
// R11: RCH3=16 -> 1024 blocks (4/CU, 16 waves/CU) for TLP on the W2 stream.
// ---------------------------------------------------------------------------
__global__ __launch_bounds__(TPB3) void k_update(const float* __restrict__ W,
                                                 const float* __restrict__ x,
                                                 const float* __restrict__ y,
                                                 const float* __restrict__ P,
                                                 const float* __restrict__ SS,
                                                 const float* __restrict__ gfp,
                                                 const float* __restrict__ gfn,
                                                 const float* __restrict__ sc,
                                                 float* __restrict__ W2) {
    const int tid = threadIdx.x;
    const int t   = blockIdx.x;
    const int c   = blockIdx.y;            // 16-row chunk, 0..255
    const int j4  = t * TPB3 + tid;        // float4 column
    const int k0  = c * RCH3;

    __shared__ float sy[RCH3], sgp[RCH3], sgn[RCH3];
    if (tid < RCH3) {
        const int r = k0 + tid;
        sy[tid]  = y[r];
        sgp[tid] = gfp[r];
        sgn[tid] = gfn[r];
    }
    const float inv_m2 = sc[0];
    __syncthreads();

    // two-level exclusive prefix in z-units.
    const int g3 = c >> 3;                 // full SS groups (16 P rows each)
    float4 a0 = make_float4(0.f, 0.f, 0.f, 0.f);
    float4 a1 = make_float4(0.f, 0.f, 0.f, 0.f);
    {
        const float4* SSp = reinterpret_cast<const float4*>(SS) + j4;
        int i = 0;
        #pragma unroll 4
        for (; i + 2 <= g3; i += 2) {
            const float4 p0 = SSp[(size_t)i * (D / 4)];
            const float4 p1 = SSp[(size_t)(i + 1) * (D / 4)];
            a0.x += p0.x; a0.y += p0.y; a0.z += p0.z; a0.w += p0.w;
            a1.x += p1.x; a1.y += p1.y; a1.z += p1.z; a1.w += p1.w;
        }
        if (i < g3) {
            const float4 p0 = SSp[(size_t)i * (D / 4)];
            a0.x += p0.x; a0.y += p0.y; a0.z += p0.z; a0.w += p0.w;
        }
    }
    {
        const float4* Pp = reinterpret_cast<const float4*>(P) + j4;
        int i = g3 * GSZ2;
        const int iend = 2 * c;            // P rows before this 16-row chunk
        #pragma unroll 4
        for (; i + 2 <= iend; i += 2) {
            const float4 p0 = Pp[(size_t)i * (D / 4)];
            const float4 p1 = Pp[(size_t)(i + 1) * (D / 4)];
            a0.x += p0.x; a0.y += p0.y; a0.z += p0.z; a0.w += p0.w;
            a1.x += p1.x; a1.y += p1.y; a1.z += p1.z; a1.w += p1.w;
        }
        if (i < iend) {
            const float4 p0 = Pp[(size_t)i * (D / 4)];
            a0.x += p0.x; a0.y += p0.y; a0.z += p0.z; a0.w += p0.w;
        }
    }
    float4 s;                               // prefix converted to y-units
    s.x = (a0.x + a1.x) * inv_m2; s.y = (a0.y + a1.y) * inv_m2;
    s.z = (a0.z + a1.z) * inv_m2; s.w = (a0.w + a1.w) * inv_m2;

    const float4 xvv = reinterpret_cast<const float4*>(x)[j4];
    const float4* Wp  = reinterpret_cast<const float4*>(W  + (size_t)k0 * D) + j4;
    float4*       W2p = reinterpret_cast<float4*>(W2 + (size_t)k0 * D) + j4;
    #pragma unroll 4
    for (int k = 0; k < RCH3; ++k) {
        const float yv = sy[k];
        const float gp = sgp[k];
        const float gn = sgn[k];
        const float4 w = Wp[(size_t)k * (D / 4)];
        s.x += yv * w.x; s.y += yv * w.y;
        s.z += yv * w.z; s.w += yv * w.w;
        vf4 o;
        {
            const float w1 = w.x + ALPHA * (yv * xvv.x - yv * s.x);
            o.x = w1 * (w1 > 0.f ? gp : gn);
        }
        {
            const float w1 = w.y + ALPHA * (yv * xvv.y - yv * s.y);
            o.y = w1 * (w1 > 0.f ? gp : gn);
        }
        {
            const float w1 = w.z + ALPHA * (yv * xvv.z - yv * s.z);
            o.z = w1 * (w1 > 0.f ? gp : gn);
        }
        {
            const float w1 = w.w + ALPHA * (yv * xvv.w - yv * s.w);
            o.w = w1 * (w1 > 0.f ? gp : gn);
        }
        __builtin_nontemporal_store(o, reinterpret_cast<vf4*>(W2p + (size_t)k * (D / 4)));
    }
}

// ===========================================================================
// Fallback (proven R6-style structure) if ws_size can't hold the 8.5 MB P/SS.
// ===========================================================================
constexpr int FCH  = 64;
constexpr int FNCH = D / FCH;
constexpr int FTPB = 128;

__global__ __launch_bounds__(256) void f_gemv(const float* __restrict__ W,
                                              const float* __restrict__ x,
                                              const float* __restrict__ b,
                                              float* __restrict__ u) {
    const int wave = threadIdx.x >> 6;
    const int lane = threadIdx.x & 63;
    const int row  = (blockIdx.x << 2) + wave;
    const float4* Wr = reinterpret_cast<const float4*>(W + (size_t)row * D);
    const float4* xv = reinterpret_cast<const float4*>(x);
    float acc = 0.f;
    #pragma unroll
    for (int it = 0; it < D / 256; ++it) {
        const float4 w  = Wr[lane + it * 64];
        const float4 xx = xv[lane + it * 64];
        acc += w.x * xx.x + w.y * xx.y + w.z * xx.z + w.w * xx.w;
    }
    #pragma unroll
    for (int off = 32; off; off >>= 1) acc += __shfl_down(acc, off, 64);
    if (lane == 0) u[row] = acc + b[row];
}

__global__ __launch_bounds__(FTPB) void f_pstats(const float* __restrict__ u,
                                                 const float* __restrict__ ea,
                                                 const float* __restrict__ W,
                                                 float* __restrict__ y_out,
                                                 float* __restrict__ ea_out,
                                                 float* __restrict__ gfp,
                                                 float* __restrict__ gfn,
                                                 float* __restrict__ P) {
    const int tid  = threadIdx.x;
    const int t    = blockIdx.x;
    const int c    = blockIdx.y;
    const int j    = t * (FTPB * 4) + tid * 4;
    const int k0   = c * FCH;
    const int wv   = tid >> 6;
    const int lane = tid & 63;

    __shared__ float sred[2];
    __shared__ float sm[2];
    __shared__ float sy[FCH];

    float lmax = 0.f;
    #pragma unroll
    for (int i = 0; i < D / FTPB; ++i)
        lmax = fmaxf(lmax, u[i * FTPB + tid]);
    #pragma unroll
    for (int off = 32; off; off >>= 1) lmax = fmaxf(lmax, __shfl_down(lmax, off, 64));
    if (lane == 0) sred[wv] = lmax;
    __syncthreads();
    if (tid == 0) sm[0] = fmaxf(sred[0], sred[1]);
    __syncthreads();
    const float m = sm[0];
    const float inv_m2 = 1.f / (m * m);

    float lsum = 0.f;
    #pragma unroll
    for (int i = 0; i < D / FTPB; ++i) {
        const int r  = i * FTPB + tid;
        const float rr = fmaxf(u[r], 0.f);
        lsum += GAMMA * ea[r] + (1.f - GAMMA) * (rr * rr * inv_m2);
    }
    #pragma unroll
    for (int off = 32; off; off >>= 1) lsum += __shfl_down(lsum, off, 64);
    if (lane == 0) sred[wv] = lsum;
    __syncthreads();
    if (tid == 0) sm[1] = sred[0] + sred[1];
    __syncthreads();
    const float inv_avg = (float)D / sm[1];

    if (tid < FCH) {
        const int r = k0 + tid;
        const float rr = fmaxf(u[r], 0.f);
        const float yv = rr * rr * inv_m2;
        sy[tid] = yv;
        if (t == 0) {
            const float ev = GAMMA * ea[r] + (1.f - GAMMA) * yv;
            const float a  = ev * inv_avg;
            const float g  = EPSC * tanhf(-EPSC * (a - 1.f)) + 1.f;
            y_out[r]  = yv;
            ea_out[r] = ev;
            gfp[r]    = g;
            gfn[r]    = 1.f / g;
        }
    }
    __syncthreads();

    const float4* Wp = reinterpret_cast<const float4*>(W + (size_t)k0 * D + j);
    float4 acc = make_float4(0.f, 0.f, 0.f, 0.f);
    #pragma unroll 8
    for (int k = 0; k < FCH; ++k) {
        const float yv = sy[k];
        const float4 w = Wp[(size_t)k * (D / 4)];
        acc.x += yv * w.x; acc.y += yv * w.y;
        acc.z += yv * w.z; acc.w += yv * w.w;
    }
    *reinterpret_cast<float4*>(P + (size_t)c * D + j) = acc;
}

__global__ __launch_bounds__(FTPB) void f_update(const float* __restrict__ W,
                                                 const float* __restrict__ x,
                                                 const float* __restrict__ y,
                                                 const float* __restrict__ P,
                                                 const float* __restrict__ gfp,
                                                 const float* __restrict__ gfn,
                                                 float* __restrict__ W2) {
    const int tid = threadIdx.x;
    const int j   = blockIdx.x * (FTPB * 4) + tid * 4;
    const int c   = blockIdx.y;
    const int k0  = c * FCH;

    __shared__ float sy[FCH], sgp[FCH], sgn[FCH];
    if (tid < FCH) {
        const int r = k0 + tid;
        sy[tid]  = y[r];
        sgp[tid] = gfp[r];
        sgn[tid] = gfn[r];
    }
    __syncthreads();

    const float4* Pp = reinterpret_cast<const float4*>(P + j);
    float4 a0 = make_float4(0.f, 0.f, 0.f, 0.f);
    float4 a1 = make_float4(0.f, 0.f, 0.f, 0.f);
    int i = 0;
    #pragma unroll 8
    for (; i + 2 <= c; i += 2) {
        const float4 p0 = Pp[(size_t)i * (D / 4)];
        const float4 p1 = Pp[(size_t)(i + 1) * (D / 4)];
        a0.x += p0.x; a0.y += p0.y; a0.z += p0.z; a0.w += p0.w;
        a1.x += p1.x; a1.y += p1.y; a1.z += p1.z; a1.w += p1.w;
    }
    if (i < c) {
        const float4 p0 = Pp[(size_t)i * (D / 4)];
        a0.x += p0.x; a0.y += p0.y; a0.z += p0.z; a0.w += p0.w;
    }
    float4 s;
    s.x = a0.x + a1.x; s.y = a0.y + a1.y;
    s.z = a0.z + a1.z; s.w = a0.w + a1.w;

    const float4 xv = *reinterpret_cast<const float4*>(x + j);
    const float4* Wp  = reinterpret_cast<const float4*>(W + (size_t)k0 * D + j);
    float4*       W2p = reinterpret_cast<float4*>(W2 + (size_t)k0 * D + j);
    #pragma unroll 4
    for (int k = 0; k < FCH; ++k) {
        const float yv = sy[k];
        const float gp = sgp[k];
        const float gn = sgn[k];
        const float4 w = Wp[(size_t)k * (D / 4)];
        s.x += yv * w.x; s.y += yv * w.y;
        s.z += yv * w.z; s.w += yv * w.w;
        vf4 o;
        { const float w1 = w.x + ALPHA * (yv * xv.x - yv * s.x); o.x = w1 * (w1 > 0.f ? gp : gn); }
        { const float w1 = w.y + ALPHA * (yv * xv.y - yv * s.y); o.y = w1 * (w1 > 0.f ? gp : gn); }
        { const float w1 = w.z + ALPHA * (yv * xv.z - yv * s.z); o.z = w1 * (w1 > 0.f ? gp : gn); }
        { const float w1 = w.w + ALPHA * (yv * xv.w - yv * s.w); o.w = w1 * (w1 > 0.f ? gp : gn); }
        __builtin_nontemporal_store(o, reinterpret_cast<vf4*>(W2p + (size_t)k * (D / 4)));
    }
}

// ===========================================================================
extern "C" void kernel_launch(void* const* d_in, const int* in_sizes, int n_in,
                              void* d_out, int out_size, void* d_ws, size_t ws_size,
                              hipStream_t stream) {
    const float* x  = (const float*)d_in[0];
    const float* W  = (const float*)d_in[1];
    const float* b  = (const float*)d_in[2];
    const float* ea = (const float*)d_in[3];

    float* out    = (float*)d_out;
    float* y_out  = out;                        // [D]
    float* W2_out = out + D;                    // [D*D]
    float* ea_out = out + D + (size_t)D * D;    // [D]

    float* ws = (float*)d_ws;
    const size_t need = (size_t)(3 * D + 16 + (size_t)NPR * D + (size_t)NSS * D)
                        * sizeof(float);

    if (ws_size >= need) {
        float* z   = ws;                        // [D]
        float* gfp = z + D;                     // [D]
        float* gfn = gfp + D;                   // [D]
        float* sc  = gfn + D;                   // [16]
        float* P   = sc + 16;                   // [NPR * D]  8 MB
        float* SS  = P + (size_t)NPR * D;       // [NSS * D]  512 KB

        k_gz<<<NPR, 256, 0, stream>>>(W, x, b, z, P);
        k_mid<<<dim3(4, NSS + 1), 256, 0, stream>>>(P, z, ea, SS, y_out, ea_out,
                                                    gfp, gfn, sc);
        k_update<<<dim3(4, NCH3), TPB3, 0, stream>>>(W, x, y_out, P, SS,
                                                     gfp, gfn, sc, W2_out);
    } else {
        float* u   = ws;                        // [D]
        float* gfp = ws + D;                    // [D]
        float* gfn = ws + 2 * D;                // [D]
        float* P   = ws + 3 * D;                // [FNCH * D] = 1 MB

        f_gemv<<<D / 4, 256, 0, stream>>>(W, x, b, u);
        dim3 grid(D / (FTPB * 4), FNCH);
        f_pstats<<<grid, FTPB, 0, stream>>>(u, ea, W, y_out, ea_out, gfp, gfn, P);
        f_update<<<grid, FTPB, 0, stream>>>(W, x, y_out, P, gfp, gfn, W2_out);
    }
}

// Round 12
// 44.715 us; speedup vs baseline: 1.5404x; 1.0437x over previous
//
#include <hip/hip_runtime.h>
#include <math.h>

// Problem constants (D_IN == D_OUT == 4096)
constexpr int   D     = 4096;
constexpr float ALPHA = 0.001f;   // heb_lr
constexpr float GAMMA = 0.99f;
constexpr float EPSC  = 0.0001f;

// --- main path decomposition ---
constexpr int RG    = 8;               // rows per k_gz block (P granularity)
constexpr int NPR   = D / RG;          // 512 P rows
constexpr int SUB   = 4;               // rows per LDS sub-batch (64 KB tile)
constexpr int GSZ2  = 16;              // P rows per supersum group
constexpr int NSS   = NPR / GSZ2;      // 32 SS rows
constexpr int RCH3  = 32;              // k_update rows per chunk
constexpr int NCH3  = D / RCH3;        // 128 -> 512 blocks
constexpr int TPB3  = 256;

using vf4 = float __attribute__((ext_vector_type(4)));

// ---------------------------------------------------------------------------
// K1: fused GEMV + chunk column-partials via LDS staging (z-units), with a
// register prefetch of sub-batch 1 issued under sub-batch 0's LDS accumulate
// (doubles in-flight HBM bytes; k_gz was latency-bound at 8 waves/CU).
// Plain P stores -- R10's agent-scope atomic stores forced P to HBM (33 MB
// WRITE) and are the pinned cause of that regression; prefetch is kept.
// ---------------------------------------------------------------------------
__global__ __launch_bounds__(256, 2) void k_gz(const float* __restrict__ W,
                                               const float* __restrict__ x,
                                               const float* __restrict__ b,
                                               float* __restrict__ z_out,
                                               float* __restrict__ P) {
    const int tid  = threadIdx.x;
    const int lane = tid & 63;
    const int wv   = tid >> 6;            // 0..3
    const int c    = blockIdx.x;          // P row (8-row chunk)
    const int k0   = c * RG;

    __shared__ float4 tile[SUB * 1024];   // 64 KB
    __shared__ float  sz[SUB];

    const float4* xv = reinterpret_cast<const float4*>(x);
    float4 acc[4] = {make_float4(0.f, 0.f, 0.f, 0.f),
                     make_float4(0.f, 0.f, 0.f, 0.f),
                     make_float4(0.f, 0.f, 0.f, 0.f),
                     make_float4(0.f, 0.f, 0.f, 0.f)};

    // ---- Stage A: sub-batch 0 -> tile + dot ----
    {
        const int row = k0 + wv;
        const float4* Wr = reinterpret_cast<const float4*>(W + (size_t)row * D);
        float a = 0.f;
        #pragma unroll
        for (int q = 0; q < 16; ++q) {
            const float4 w = Wr[lane + q * 64];
            tile[wv * 1024 + lane + q * 64] = w;
            const float4 xx = xv[lane + q * 64];
            a += w.x * xx.x + w.y * xx.y + w.z * xx.z + w.w * xx.w;
        }
        #pragma unroll
        for (int off = 32; off; off >>= 1) a += __shfl_down(a, off, 64);
        if (lane == 0) {
            const float u = a + b[row];
            const float r = fmaxf(u, 0.f);
            const float zz = r * r;              // z = relu(u)^2 (LAMB = 2)
            sz[wv] = zz;
            z_out[row] = zz;
        }
    }
    __syncthreads();                             // tile + sz ready

    // ---- Stage B: prefetch sub-batch 1 to regs; accumulate sub-batch 0 ----
    float4 r1[16];                               // 64 VGPRs, statically indexed
    const int row1 = k0 + SUB + wv;
    {
        const float4* Wr1 = reinterpret_cast<const float4*>(W + (size_t)row1 * D);
        #pragma unroll
        for (int q = 0; q < 16; ++q) r1[q] = Wr1[lane + q * 64];  // issue early
    }
    #pragma unroll
    for (int c4 = 0; c4 < 4; ++c4) {             // hides the loads above
        const int col = tid + c4 * 256;
        #pragma unroll
        for (int r = 0; r < SUB; ++r) {
            const float4 w = tile[r * 1024 + col];
            const float zz = sz[r];
            acc[c4].x += zz * w.x; acc[c4].y += zz * w.y;
            acc[c4].z += zz * w.z; acc[c4].w += zz * w.w;
        }
    }
    float a1 = 0.f;
    #pragma unroll
    for (int q = 0; q < 16; ++q) {
        const float4 xx = xv[lane + q * 64];
        a1 += r1[q].x * xx.x + r1[q].y * xx.y + r1[q].z * xx.z + r1[q].w * xx.w;
    }
    __syncthreads();                             // done reading tile (sb0)

    // ---- Stage C: sub-batch 1 -> tile; z ----
    #pragma unroll
    for (int q = 0; q < 16; ++q) tile[wv * 1024 + lane + q * 64] = r1[q];
    #pragma unroll
    for (int off = 32; off; off >>= 1) a1 += __shfl_down(a1, off, 64);
    if (lane == 0) {
        const float u = a1 + b[row1];
        const float r = fmaxf(u, 0.f);
        const float zz = r * r;
        sz[wv] = zz;
        z_out[row1] = zz;
    }
    __syncthreads();

    // ---- Stage D: accumulate sub-batch 1; plain P store ----
    #pragma unroll
    for (int c4 = 0; c4 < 4; ++c4) {
        const int col = tid + c4 * 256;
        #pragma unroll
        for (int r = 0; r < SUB; ++r) {
            const float4 w = tile[r * 1024 + col];
            const float zz = sz[r];
            acc[c4].x += zz * w.x; acc[c4].y += zz * w.y;
            acc[c4].z += zz * w.z; acc[c4].w += zz * w.w;
        }
    }
    float4* Pp = reinterpret_cast<float4*>(P + (size_t)c * D);
    #pragma unroll
    for (int c4 = 0; c4 < 4; ++c4) Pp[tid + c4 * 256] = acc[c4];
}

// ---------------------------------------------------------------------------
// K2: pure group super-sums SS[g,:] = sum of 16 P rows. 128 blocks, ~1 us.
// (Stats moved into k_update's redundant per-block computation.)
// ---------------------------------------------------------------------------
__global__ __launch_bounds__(256) void k_ss(const float* __restrict__ P,
                                            float* __restrict__ SS) {
    const int j4 = blockIdx.x * 256 + threadIdx.x;   // float4 column
    const int g  = blockIdx.y;
    const float4* Pp = reinterpret_cast<const float4*>(P)
                     + (size_t)(g * GSZ2) * (D / 4) + j4;
    float4 a = make_float4(0.f, 0.f, 0.f, 0.f);
    #pragma unroll
    for (int i = 0; i < GSZ2; ++i) {
        const float4 p = Pp[(size_t)i * (D / 4)];
        a.x += p.x; a.y += p.y; a.z += p.z; a.w += p.w;
    }
    reinterpret_cast<float4*>(SS)[(size_t)g * (D / 4) + j4] = a;
}

// ---------------------------------------------------------------------------
// K3: redundant per-block stats from z/ea (bitwise-identical reduction order
// across blocks; R5/R6/R7-proven) + two-level exclusive prefix (<=31 SS +
// <=12 P rows, L2-resident) + in-chunk inclusive scan + Hebbian delta +
// sign-split decay + nt W2 store. t==0 blocks write y/ea outputs.
// ---------------------------------------------------------------------------
__global__ __launch_bounds__(TPB3) void k_update(const float* __restrict__ W,
                                                 const float* __restrict__ x,
                                                 const float* __restrict__ z,
                                                 const float* __restrict__ ea,
                                                 const float* __restrict__ P,
                                                 const float* __restrict__ SS,
                                                 float* __restrict__ y_out,
                                                 float* __restrict__ ea_out,
                                                 float* __restrict__ W2) {
    const int tid  = threadIdx.x;
    const int t    = blockIdx.x;
    const int c    = blockIdx.y;           // 32-row chunk, 0..127
    const int j4   = t * TPB3 + tid;       // float4 column
    const int k0   = c * RCH3;
    const int wv   = tid >> 6;
    const int lane = tid & 63;

    __shared__ float sred[4];
    __shared__ float sm[2];                // m^2, sum(ea_new)
    __shared__ float sy[RCH3], sgp[RCH3], sgn[RCH3];

    // stats pass 1: m^2 = max(z) (square is monotone on relu output)
    float lmax = 0.f;
    #pragma unroll
    for (int i = 0; i < D / TPB3; ++i)
        lmax = fmaxf(lmax, z[i * TPB3 + tid]);
    #pragma unroll
    for (int off = 32; off; off >>= 1) lmax = fmaxf(lmax, __shfl_down(lmax, off, 64));
    if (lane == 0) sred[wv] = lmax;
    __syncthreads();
    if (tid == 0) sm[0] = fmaxf(fmaxf(sred[0], sred[1]), fmaxf(sred[2], sred[3]));
    __syncthreads();
    const float inv_m2 = 1.f / sm[0];

    // stats pass 2: sum(ea_new)
    float lsum = 0.f;
    #pragma unroll
    for (int i = 0; i < D / TPB3; ++i) {
        const int r = i * TPB3 + tid;
        lsum += GAMMA * ea[r] + (1.f - GAMMA) * (z[r] * inv_m2);
    }
    #pragma unroll
    for (int off = 32; off; off >>= 1) lsum += __shfl_down(lsum, off, 64);
    if (lane == 0) sred[wv] = lsum;        // safe: all passed prior sync
    __syncthreads();
    if (tid == 0) sm[1] = (sred[0] + sred[1]) + (sred[2] + sred[3]);
    __syncthreads();
    const float inv_avg = (float)D / sm[1];

    // own-chunk y / gf; t==0 blocks write y / ea globals
    if (tid < RCH3) {
        const int r = k0 + tid;
        const float yv = z[r] * inv_m2;
        const float ev = GAMMA * ea[r] + (1.f - GAMMA) * yv;
        const float aa = ev * inv_avg;
        const float gg = EPSC * tanhf(-EPSC * (aa - 1.f)) + 1.f;
        sy[tid]  = yv;
        sgp[tid] = gg;
        sgn[tid] = 1.f / gg;
        if (t == 0) { y_out[r] = yv; ea_out[r] = ev; }
    }
    __syncthreads();

    // two-level exclusive prefix in z-units.
    const int g3 = c >> 2;                 // full SS groups (16 P rows each)
    float4 a0 = make_float4(0.f, 0.f, 0.f, 0.f);
    float4 a1 = make_float4(0.f, 0.f, 0.f, 0.f);
    {
        const float4* SSp = reinterpret_cast<const float4*>(SS) + j4;
        int i = 0;
        #pragma unroll 4
        for (; i + 2 <= g3; i += 2) {
            const float4 p0 = SSp[(size_t)i * (D / 4)];
            const float4 p1 = SSp[(size_t)(i + 1) * (D / 4)];
            a0.x += p0.x; a0.y += p0.y; a0.z += p0.z; a0.w += p0.w;
            a1.x += p1.x; a1.y += p1.y; a1.z += p1.z; a1.w += p1.w;
        }
        if (i < g3) {
            const float4 p0 = SSp[(size_t)i * (D / 4)];
            a0.x += p0.x; a0.y += p0.y; a0.z += p0.z; a0.w += p0.w;
        }
    }
    {
        const float4* Pp = reinterpret_cast<const float4*>(P) + j4;
        int i = g3 * GSZ2;
        const int iend = 4 * c;            // P rows before this 32-row chunk
        #pragma unroll 4
        for (; i + 2 <= iend; i += 2) {
            const float4 p0 = Pp[(size_t)i * (D / 4)];
            const float4 p1 = Pp[(size_t)(i + 1) * (D / 4)];
            a0.x += p0.x; a0.y += p0.y; a0.z += p0.z; a0.w += p0.w;
            a1.x += p1.x; a1.y += p1.y; a1.z += p1.z; a1.w += p1.w;
        }
        if (i < iend) {
            const float4 p0 = Pp[(size_t)i * (D / 4)];
            a0.x += p0.x; a0.y += p0.y; a0.z += p0.z; a0.w += p0.w;
        }
    }
    float4 s;                               // prefix converted to y-units
    s.x = (a0.x + a1.x) * inv_m2; s.y = (a0.y + a1.y) * inv_m2;
    s.z = (a0.z + a1.z) * inv_m2; s.w = (a0.w + a1.w) * inv_m2;

    const float4 xvv = reinterpret_cast<const float4*>(x)[j4];
    const float4* Wp  = reinterpret_cast<const float4*>(W  + (size_t)k0 * D) + j4;
    float4*       W2p = reinterpret_cast<float4*>(W2 + (size_t)k0 * D) + j4;
    #pragma unroll 4
    for (int k = 0; k < RCH3; ++k) {
        const float yv = sy[k];
        const float gp = sgp[k];
        const float gn = sgn[k];
        const float4 w = Wp[(size_t)k * (D / 4)];
        s.x += yv * w.x; s.y += yv * w.y;
        s.z += yv * w.z; s.w += yv * w.w;
        vf4 o;
        {
            const float w1 = w.x + ALPHA * (yv * xvv.x - yv * s.x);
            o.x = w1 * (w1 > 0.f ? gp : gn);
        }
        {
            const float w1 = w.y + ALPHA * (yv * xvv.y - yv * s.y);
            o.y = w1 * (w1 > 0.f ? gp : gn);
        }
        {
            const float w1 = w.z + ALPHA * (yv * xvv.z - yv * s.z);
            o.z = w1 * (w1 > 0.f ? gp : gn);
        }
        {
            const float w1 = w.w + ALPHA * (yv * xvv.w - yv * s.w);
            o.w = w1 * (w1 > 0.f ? gp : gn);
        }
        __builtin_nontemporal_store(o, reinterpret_cast<vf4*>(W2p + (size_t)k * (D / 4)));
    }
}

// ===========================================================================
// Fallback (proven R6-style structure) if ws_size can't hold the 8.5 MB P/SS.
// ===========================================================================
constexpr int FCH  = 64;
constexpr int FNCH = D / FCH;
constexpr int FTPB = 128;

__global__ __launch_bounds__(256) void f_gemv(const float* __restrict__ W,
                                              const float* __restrict__ x,
                                              const float* __restrict__ b,
                                              float* __restrict__ u) {
    const int wave = threadIdx.x >> 6;
    const int lane = threadIdx.x & 63;
    const int row  = (blockIdx.x << 2) + wave;
    const float4* Wr = reinterpret_cast<const float4*>(W + (size_t)row * D);
    const float4* xv = reinterpret_cast<const float4*>(x);
    float acc = 0.f;
    #pragma unroll
    for (int it = 0; it < D / 256; ++it) {
        const float4 w  = Wr[lane + it * 64];
        const float4 xx = xv[lane + it * 64];
        acc += w.x * xx.x + w.y * xx.y + w.z * xx.z + w.w * xx.w;
    }
    #pragma unroll
    for (int off = 32; off; off >>= 1) acc += __shfl_down(acc, off, 64);
    if (lane == 0) u[row] = acc + b[row];
}

__global__ __launch_bounds__(FTPB) void f_pstats(const float* __restrict__ u,
                                                 const float* __restrict__ ea,
                                                 const float* __restrict__ W,
                                                 float* __restrict__ y_out,
                                                 float* __restrict__ ea_out,
                                                 float* __restrict__ gfp,
                                                 float* __restrict__ gfn,
                                                 float* __restrict__ P) {
    const int tid  = threadIdx.x;
    const int t    = blockIdx.x;
    const int c    = blockIdx.y;
    const int j    = t * (FTPB * 4) + tid * 4;
    const int k0   = c * FCH;
    const int wv   = tid >> 6;
    const int lane = tid & 63;

    __shared__ float sred[2];
    __shared__ float sm[2];
    __shared__ float sy[FCH];

    float lmax = 0.f;
    #pragma unroll
    for (int i = 0; i < D / FTPB; ++i)
        lmax = fmaxf(lmax, u[i * FTPB + tid]);
    #pragma unroll
    for (int off = 32; off; off >>= 1) lmax = fmaxf(lmax, __shfl_down(lmax, off, 64));
    if (lane == 0) sred[wv] = lmax;
    __syncthreads();
    if (tid == 0) sm[0] = fmaxf(sred[0], sred[1]);
    __syncthreads();
    const float m = sm[0];
    const float inv_m2 = 1.f / (m * m);

    float lsum = 0.f;
    #pragma unroll
    for (int i = 0; i < D / FTPB; ++i) {
        const int r  = i * FTPB + tid;
        const float rr = fmaxf(u[r], 0.f);
        lsum += GAMMA * ea[r] + (1.f - GAMMA) * (rr * rr * inv_m2);
    }
    #pragma unroll
    for (int off = 32; off; off >>= 1) lsum += __shfl_down(lsum, off, 64);
    if (lane == 0) sred[wv] = lsum;
    __syncthreads();
    if (tid == 0) sm[1] = sred[0] + sred[1];
    __syncthreads();
    const float inv_avg = (float)D / sm[1];

    if (tid < FCH) {
        const int r = k0 + tid;
        const float rr = fmaxf(u[r], 0.f);
        const float yv = rr * rr * inv_m2;
        sy[tid] = yv;
        if (t == 0) {
            const float ev = GAMMA * ea[r] + (1.f - GAMMA) * yv;
            const float a  = ev * inv_avg;
            const float g  = EPSC * tanhf(-EPSC * (a - 1.f)) + 1.f;
            y_out[r]  = yv;
            ea_out[r] = ev;
            gfp[r]    = g;
            gfn[r]    = 1.f / g;
        }
    }
    __syncthreads();

    const float4* Wp = reinterpret_cast<const float4*>(W + (size_t)k0 * D + j);
    float4 acc = make_float4(0.f, 0.f, 0.f, 0.f);
    #pragma unroll 8
    for (int k = 0; k < FCH; ++k) {
        const float yv = sy[k];
        const float4 w = Wp[(size_t)k * (D / 4)];
        acc.x += yv * w.x; acc.y += yv * w.y;
        acc.z += yv * w.z; acc.w += yv * w.w;
    }
    *reinterpret_cast<float4*>(P + (size_t)c * D + j) = acc;
}

__global__ __launch_bounds__(FTPB) void f_update(const float* __restrict__ W,
                                                 const float* __restrict__ x,
                                                 const float* __restrict__ y,
                                                 const float* __restrict__ P,
                                                 const float* __restrict__ gfp,
                                                 const float* __restrict__ gfn,
                                                 float* __restrict__ W2) {
    const int tid = threadIdx.x;
    const int j   = blockIdx.x * (FTPB * 4) + tid * 4;
    const int c   = blockIdx.y;
    const int k0  = c * FCH;

    __shared__ float sy[FCH], sgp[FCH], sgn[FCH];
    if (tid < FCH) {
        const int r = k0 + tid;
        sy[tid]  = y[r];
        sgp[tid] = gfp[r];
        sgn[tid] = gfn[r];
    }
    __syncthreads();

    const float4* Pp = reinterpret_cast<const float4*>(P + j);
    float4 a0 = make_float4(0.f, 0.f, 0.f, 0.f);
    float4 a1 = make_float4(0.f, 0.f, 0.f, 0.f);
    int i = 0;
    #pragma unroll 8
    for (; i + 2 <= c; i += 2) {
        const float4 p0 = Pp[(size_t)i * (D / 4)];
        const float4 p1 = Pp[(size_t)(i + 1) * (D / 4)];
        a0.x += p0.x; a0.y += p0.y; a0.z += p0.z; a0.w += p0.w;
        a1.x += p1.x; a1.y += p1.y; a1.z += p1.z; a1.w += p1.w;
    }
    if (i < c) {
        const float4 p0 = Pp[(size_t)i * (D / 4)];
        a0.x += p0.x; a0.y += p0.y; a0.z += p0.z; a0.w += p0.w;
    }
    float4 s;
    s.x = a0.x + a1.x; s.y = a0.y + a1.y;
    s.z = a0.z + a1.z; s.w = a0.w + a1.w;

    const float4 xv = *reinterpret_cast<const float4*>(x + j);
    const float4* Wp  = reinterpret_cast<const float4*>(W + (size_t)k0 * D + j);
    float4*       W2p = reinterpret_cast<float4*>(W2 + (size_t)k0 * D + j);
    #pragma unroll 4
    for (int k = 0; k < FCH; ++k) {
        const float yv = sy[k];
        const float gp = sgp[k];
        const float gn = sgn[k];
        const float4 w = Wp[(size_t)k * (D / 4)];
        s.x += yv * w.x; s.y += yv * w.y;
        s.z += yv * w.z; s.w += yv * w.w;
        vf4 o;
        { const float w1 = w.x + ALPHA * (yv * xv.x - yv * s.x); o.x = w1 * (w1 > 0.f ? gp : gn); }
        { const float w1 = w.y + ALPHA * (yv * xv.y - yv * s.y); o.y = w1 * (w1 > 0.f ? gp : gn); }
        { const float w1 = w.z + ALPHA * (yv * xv.z - yv * s.z); o.z = w1 * (w1 > 0.f ? gp : gn); }
        { const float w1 = w.w + ALPHA * (yv * xv.w - yv * s.w); o.w = w1 * (w1 > 0.f ? gp : gn); }
        __builtin_nontemporal_store(o, reinterpret_cast<vf4*>(W2p + (size_t)k * (D / 4)));
    }
}

// ===========================================================================
extern "C" void kernel_launch(void* const* d_in, const int* in_sizes, int n_in,
                              void* d_out, int out_size, void* d_ws, size_t ws_size,
                              hipStream_t stream) {
    const float* x  = (const float*)d_in[0];
    const float* W  = (const float*)d_in[1];
    const float* b  = (const float*)d_in[2];
    const float* ea = (const float*)d_in[3];

    float* out    = (float*)d_out;
    float* y_out  = out;                        // [D]
    float* W2_out = out + D;                    // [D*D]
    float* ea_out = out + D + (size_t)D * D;    // [D]

    float* ws = (float*)d_ws;
    const size_t need = (size_t)(D + (size_t)NPR * D + (size_t)NSS * D)
                        * sizeof(float);

    if (ws_size >= need) {
        float* z  = ws;                         // [D]         16 KB
        float* P  = z + D;                      // [NPR * D]   8 MB
        float* SS = P + (size_t)NPR * D;        // [NSS * D]   512 KB

        k_gz<<<NPR, 256, 0, stream>>>(W, x, b, z, P);
        k_ss<<<dim3(4, NSS), 256, 0, stream>>>(P, SS);
        k_update<<<dim3(4, NCH3), TPB3, 0, stream>>>(W, x, z, ea, P, SS,
                                                     y_out, ea_out, W2_out);
    } else {
        float* u   = ws;                        // [D]
        float* gfp = ws + D;                    // [D]
        float* gfn = ws + 2 * D;                // [D]
        float* P   = ws + 3 * D;                // [FNCH * D] = 1 MB

        f_gemv<<<D / 4, 256, 0, stream>>>(W, x, b, u);
        dim3 grid(D / (FTPB * 4), FNCH);
        f_pstats<<<grid, FTPB, 0, stream>>>(u, ea, W, y_out, ea_out, gfp, gfn, P);
        f_update<<<grid, FTPB, 0, stream>>>(W, x, y_out, P, gfp, gfn, W2_out);
    }
}